// Round 8
// baseline (362.759 us; speedup 1.0000x reference)
//
#include <hip/hip_runtime.h>
#include <hip/hip_cooperative_groups.h>
#include <stdint.h>

namespace cg = cooperative_groups;

// Problem constants (fixed by the reference)
#define BN    8192    // batch
#define DK    256     // dim
#define PN    4096    // pairs
#define MAXP  16      // max partners tracked per row (Poisson(1); P(>16) ~ 1e-15)
#define RANK_ASC 6553 // ascending rank of first kept element (top-1639 = 0.8 quantile)
#define QSTEP 0.02f   // logit quantization step: code = round(5*cos/QSTEP)+128 in [1,255]
#define MAXGRID 512   // cooperative grid cap; actual grid = min(MAXGRID, occupancy*CUs)
#define NCU   256

typedef __bf16  bf16_8 __attribute__((ext_vector_type(8)));
typedef __bf16  bf16_4 __attribute__((ext_vector_type(4)));
typedef float   f32x4  __attribute__((ext_vector_type(4)));

__device__ __forceinline__ void gload_lds16(const void* g, void* l) {
  __builtin_amdgcn_global_load_lds(
      (const __attribute__((address_space(1))) unsigned int*)g,
      (__attribute__((address_space(3))) unsigned int*)l, 16, 0, 0);
}

// ------------------------------------------------ parallel bin finder (256 bins)
__device__ __forceinline__ void find_bin_256(const unsigned* hist, int rank,
                                             int* sh, unsigned* wtot) {
  const int tid = threadIdx.x, lane = tid & 63, w = tid >> 6;
  unsigned x = hist[tid];
  unsigned pref = x;
  #pragma unroll
  for (int o = 1; o < 64; o <<= 1) {
    unsigned y = __shfl_up(pref, o);
    if (lane >= o) pref += y;
  }
  if (lane == 63) wtot[w] = pref;
  __syncthreads();
  unsigned woff = 0;
  for (int i = 0; i < w; ++i) woff += wtot[i];
  unsigned incl = pref + woff, excl = incl - x;
  if ((unsigned)rank >= excl && (unsigned)rank < incl) { sh[0] = tid; sh[1] = rank - (int)excl; }
  __syncthreads();
}

__device__ __forceinline__ float block_sum4(float x, float* red4) {
  const int lane = threadIdx.x & 63, w = threadIdx.x >> 6;
  #pragma unroll
  for (int o = 32; o; o >>= 1) x += __shfl_xor(x, o);
  __syncthreads();
  if (lane == 0) red4[w] = x;
  __syncthreads();
  return red4[0] + red4[1] + red4[2] + red4[3];
}

struct Params {
  const float* emb; const int2* pairs;
  float* E; __bf16* Ebf; float* S; float* pos;
  int* pcnt; int* parts; int* rlist; int* cnt;
  uint32_t* out4; float* out;
};

union __align__(16) SMem {
  struct { __bf16 A[128 * 32]; __bf16 B[128 * 32]; } g;              // 16 KB
  struct { unsigned hist[4][4][256]; unsigned total[4][256];
           int plist[4][MAXP + 1]; int npl[4]; int growl[4];
           int sh[2]; unsigned wtot[4]; float redf[4]; } rs;         // ~20.6 KB
  struct { uint32_t v[PN]; unsigned hist[256];
           int sh[2]; unsigned wtot[4]; float red4[4]; } fin;        // ~17.1 KB
};

// ======================= cooperative mega kernel =======================
// All phase bodies are the (verified) R6 kernels, grid-strided.
__global__ void __launch_bounds__(256, 2) mega_kernel(Params prm) {
  __shared__ SMem sm;
  cg::grid_group grid = cg::this_grid();
  const int tid  = threadIdx.x;
  const int lane = tid & 63;
  const int wib  = tid >> 6;
  const int nthr  = gridDim.x * 256;
  const int nwave = gridDim.x * 4;
  const int gix  = blockIdx.x * 256 + tid;
  const int wv   = blockIdx.x * 4 + wib;

  // ---------------- Phase A: clear ----------------
  for (int i = gix; i < BN; i += nthr) { prm.pcnt[i] = 0; prm.rlist[i] = 0; }
  if (gix == 0) prm.cnt[0] = 0;
  grid.sync();

  // ---------------- Phase B: normalize + pair scatter ----------------
  for (int row = wv; row < BN; row += nwave) {
    float4 x = ((const float4*)(prm.emb + (size_t)row * DK))[lane];
    float ss = x.x * x.x + x.y * x.y + x.z * x.z + x.w * x.w;
    #pragma unroll
    for (int o = 32; o; o >>= 1) ss += __shfl_xor(ss, o);
    float nrm = fmaxf(sqrtf(ss), 1e-8f);
    float4 e;
    e.x = x.x / nrm; e.y = x.y / nrm; e.z = x.z / nrm; e.w = x.w / nrm;
    ((float4*)(prm.E + (size_t)row * DK))[lane] = e;
    bf16_4 b;
    b[0] = (__bf16)e.x; b[1] = (__bf16)e.y; b[2] = (__bf16)e.z; b[3] = (__bf16)e.w;
    *(bf16_4*)(prm.Ebf + (size_t)row * DK + lane * 4) = b;
  }
  for (int p = gix; p < PN; p += nthr) {
    int2 pr = prm.pairs[p];
    int ix = atomicAdd(&prm.pcnt[pr.x], 1);
    if (ix < MAXP) prm.parts[pr.x * MAXP + ix] = pr.y;
    int iy = atomicAdd(&prm.pcnt[pr.y], 1);
    if (iy < MAXP) prm.parts[pr.y * MAXP + iy] = pr.x;
  }
  grid.sync();

  // ---------------- Phase C: compact + pos ----------------
  for (int i = gix; i < BN; i += nthr) {
    if (prm.pcnt[i] > 0) {
      int pos = atomicAdd(prm.cnt, 1);
      prm.rlist[pos] = i;
    }
  }
  for (int p = wv; p < PN; p += nwave) {
    int2 pr = prm.pairs[p];
    float4 a = ((const float4*)(prm.E + (size_t)pr.x * DK))[lane];
    float4 b = ((const float4*)(prm.E + (size_t)pr.y * DK))[lane];
    float d = a.x * b.x + a.y * b.y + a.z * b.z + a.w * b.w;
    #pragma unroll
    for (int o = 32; o; o >>= 1) d += __shfl_xor(d, o);
    if (lane == 0) prm.pos[p] = __expf(5.0f * d);
  }
  grid.sync();

  // ---------------- Phase D: GEMM -> logit codes ----------------
  {
    const int cnt   = prm.cnt[0];
    const int nrb   = (cnt + 127) >> 7;
    const int ntile = nrb * (BN / 128);
    const int wm = wib >> 1, wn = wib & 1;
    const int r0  = tid >> 2;
    const int seg = tid & 3;
    __bf16* la0 = &sm.g.A[tid * 8];
    __bf16* la1 = &sm.g.A[2048 + tid * 8];
    __bf16* lb0 = &sm.g.B[tid * 8];
    __bf16* lb1 = &sm.g.B[2048 + tid * 8];

    for (int t = blockIdx.x; t < ntile; t += gridDim.x) {
      const int trow = (t >> 6) * 128;
      const int tcol = (t & 63) * 128;
      const int ga0 = prm.rlist[trow + r0];
      const int ga1 = prm.rlist[trow + 64 + r0];
      const __bf16* pa0 = prm.Ebf + (size_t)ga0 * DK + seg * 8;
      const __bf16* pa1 = prm.Ebf + (size_t)ga1 * DK + seg * 8;
      const __bf16* pb0 = prm.Ebf + (size_t)(tcol + r0) * DK + seg * 8;
      const __bf16* pb1 = prm.Ebf + (size_t)(tcol + 64 + r0) * DK + seg * 8;

      f32x4 acc[4][4];
      #pragma unroll
      for (int i = 0; i < 4; ++i)
        #pragma unroll
        for (int j = 0; j < 4; ++j) {
          f32x4 z = {0.f, 0.f, 0.f, 0.f};
          acc[i][j] = z;
        }

      for (int kt = 0; kt < 8; ++kt) {
        const int k0 = kt * 32;
        __syncthreads();
        gload_lds16(pa0 + k0, la0);
        gload_lds16(pa1 + k0, la1);
        gload_lds16(pb0 + k0, lb0);
        gload_lds16(pb1 + k0, lb1);
        __syncthreads();
        bf16_8 af[4], bfg[4];
        #pragma unroll
        for (int q = 0; q < 4; ++q) {
          af[q]  = *(const bf16_8*)&sm.g.A[(wm * 64 + q * 16 + (lane & 15)) * 32 + (lane >> 4) * 8];
          bfg[q] = *(const bf16_8*)&sm.g.B[(wn * 64 + q * 16 + (lane & 15)) * 32 + (lane >> 4) * 8];
        }
        #pragma unroll
        for (int i = 0; i < 4; ++i)
          #pragma unroll
          for (int j = 0; j < 4; ++j)
            acc[i][j] = __builtin_amdgcn_mfma_f32_16x16x32_bf16(af[i], bfg[j], acc[i][j], 0, 0, 0);
      }

      const int crow = trow + wm * 64 + (lane >> 4) * 4;  // %4 == 0
      const int ccol = tcol + wn * 64 + (lane & 15);
      #pragma unroll
      for (int i = 0; i < 4; ++i) {
        const int gidx = (crow + i * 16) >> 2;
        #pragma unroll
        for (int j = 0; j < 4; ++j) {
          const int col = ccol + j * 16;
          uint32_t u = 0;
          #pragma unroll
          for (int r = 0; r < 4; ++r) {
            int c = (int)rintf(fmaf(acc[i][j][r], 250.0f, 128.0f));
            c = c < 1 ? 1 : (c > 255 ? 255 : c);
            u |= (uint32_t)c << (8 * r);
          }
          prm.out4[(size_t)gidx * BN + col] = u;
        }
      }
    }
  }
  grid.sync();

  // ---------------- Phase E: row stats from code histogram ----------------
  {
    const int cnt = prm.cnt[0];
    for (int g = blockIdx.x; g * 4 < cnt; g += gridDim.x) {
      __syncthreads();   // protect LDS reuse across loop iterations
      uint4 rv[8];
      const uint4* src = (const uint4*)(prm.out4 + (size_t)g * BN);
      #pragma unroll
      for (int q = 0; q < 8; ++q) rv[q] = src[q * 256 + tid];

      if (tid < 4) {
        int rr = g * 4 + tid;
        int grow = (rr < cnt) ? prm.rlist[rr] : -1;
        sm.rs.growl[tid] = grow;
        int np = 0;
        if (grow >= 0) {
          np = prm.pcnt[grow]; if (np > MAXP) np = MAXP;
          for (int e = 0; e < np; ++e) sm.rs.plist[tid][e] = prm.parts[grow * MAXP + e];
          sm.rs.plist[tid][np] = grow;   // diagonal
          np++;
        }
        sm.rs.npl[tid] = np;
      }
      #pragma unroll
      for (int k = 0; k < 16; ++k) ((unsigned*)sm.rs.hist)[k * 256 + tid] = 0;
      __syncthreads();

      #pragma unroll
      for (int r4 = 0; r4 < 4; ++r4) {
        const int np = sm.rs.npl[r4];
        for (int e = 0; e < np; ++e) {
          int c = sm.rs.plist[r4][e];
          int t = c >> 2;
          if ((t & 255) == tid) {
            unsigned* wp = (unsigned*)&rv[t >> 8];
            wp[c & 3] &= ~(0xFFu << (r4 * 8));
          }
        }
      }

      unsigned* h = (unsigned*)sm.rs.hist[wib];
      #pragma unroll
      for (int q = 0; q < 8; ++q) {
        #pragma unroll
        for (int word = 0; word < 4; ++word) {
          unsigned dw = ((const unsigned*)&rv[q])[word];
          atomicAdd(&h[0 * 256 + (dw & 255u)], 1u);
          atomicAdd(&h[1 * 256 + ((dw >> 8) & 255u)], 1u);
          atomicAdd(&h[2 * 256 + ((dw >> 16) & 255u)], 1u);
          atomicAdd(&h[3 * 256 + (dw >> 24)], 1u);
        }
      }
      __syncthreads();
      #pragma unroll
      for (int r4 = 0; r4 < 4; ++r4)
        sm.rs.total[r4][tid] = sm.rs.hist[0][r4][tid] + sm.rs.hist[1][r4][tid]
                             + sm.rs.hist[2][r4][tid] + sm.rs.hist[3][r4][tid];
      __syncthreads();

      const float val = __expf((float)(tid - 128) * QSTEP);
      for (int r4 = 0; r4 < 4; ++r4) {
        find_bin_256(sm.rs.total[r4], RANK_ASC, sm.rs.sh, sm.rs.wtot);
        const int b    = sm.rs.sh[0];
        const int need = (int)sm.rs.total[r4][b] - sm.rs.sh[1];
        float contrib = (tid > b) ? (float)sm.rs.total[r4][tid] * val
                      : (tid == b) ? (float)need * val : 0.f;
        #pragma unroll
        for (int o = 32; o; o >>= 1) contrib += __shfl_xor(contrib, o);
        __syncthreads();
        if (lane == 0) sm.rs.redf[wib] = contrib;
        __syncthreads();
        if (tid == 0 && sm.rs.growl[r4] >= 0)
          prm.S[sm.rs.growl[r4]] = sm.rs.redf[0] + sm.rs.redf[1] + sm.rs.redf[2] + sm.rs.redf[3];
        __syncthreads();
      }
    }
  }
  grid.sync();

  // ---------------- Phase F: finale (block 0 only) ----------------
  if (blockIdx.x == 0) {
    for (int i = tid; i < PN; i += 256) sm.fin.v[i] = ((const uint32_t*)prm.pos)[i];
    __syncthreads();
    int rank = 819;                 // 0.2 * 4095 exactly
    uint32_t prefix = 0;
    for (int pass = 0; pass < 4; ++pass) {
      const int shift = 24 - pass * 8;
      sm.fin.hist[tid] = 0;
      __syncthreads();
      for (int i = tid; i < PN; i += 256) {
        uint32_t x = sm.fin.v[i];
        bool match = (pass == 0) || ((x >> (shift + 8)) == (prefix >> (shift + 8)));
        if (match) atomicAdd(&sm.fin.hist[(x >> shift) & 255u], 1u);
      }
      __syncthreads();
      find_bin_256(sm.fin.hist, rank, sm.fin.sh, sm.fin.wtot);
      prefix |= ((uint32_t)sm.fin.sh[0]) << shift;
      rank = sm.fin.sh[1];
      __syncthreads();
    }
    float thr; __builtin_memcpy(&thr, &prefix, 4);

    float n = 0.f, sl = 0.f, sp = 0.f, sp2 = 0.f;
    for (int r = tid; r < PN; r += 256) {
      float p; uint32_t b = sm.fin.v[r]; __builtin_memcpy(&p, &b, 4);
      if (p <= thr) { n += 1.f; sl += __logf(p); sp += p; sp2 += p * p; }
    }
    float t = 0.f, u = 0.f, vv = 0.f;
    for (int c = tid; c < PN; c += 256) {
      int2 pr = prm.pairs[c];
      float s1 = prm.S[pr.x], s2 = prm.S[pr.y];
      float i1 = 1.f / s1, i2 = 1.f / s2;
      t += __logf(s1) + __logf(s2);
      u += i1 + i2;
      vv += i1 * i1 + i2 * i2;
    }
    const float N   = block_sum4(n, sm.fin.red4);
    const float SL  = block_sum4(sl, sm.fin.red4);
    const float SP  = block_sum4(sp, sm.fin.red4);
    const float SP2 = block_sum4(sp2, sm.fin.red4);
    const float T   = block_sum4(t, sm.fin.red4);
    const float U   = block_sum4(u, sm.fin.red4);
    const float V   = block_sum4(vv, sm.fin.red4);
    if (tid == 0) {
      double num = (double)N * T - 2.0 * (double)PN * (double)SL
                 + (double)SP * U - 0.5 * (double)SP2 * V;
      prm.out[0] = (float)(num / (2.0 * (double)PN));
    }
  }
}

// ======================= fallback: verified R6 multi-kernel path =======================
__global__ void prep_clear_kernel(int* pcount, int* rowlist, int* cnt) {
  const int i = blockIdx.x * 256 + threadIdx.x;
  if (i < BN) { pcount[i] = 0; rowlist[i] = 0; }
  if (i == 0) cnt[0] = 0;
}

__global__ void prep_pairs_kernel(const int2* __restrict__ pairs,
                                  int* pcount, int* partners) {
  const int p = blockIdx.x * 256 + threadIdx.x;
  if (p >= PN) return;
  int2 pr = pairs[p];
  int ix = atomicAdd(&pcount[pr.x], 1);
  if (ix < MAXP) partners[pr.x * MAXP + ix] = pr.y;
  int iy = atomicAdd(&pcount[pr.y], 1);
  if (iy < MAXP) partners[pr.y * MAXP + iy] = pr.x;
}

__global__ void prep_compact_kernel(const int* __restrict__ pcount,
                                    int* rowlist, int* cnt) {
  const int i = blockIdx.x * 256 + threadIdx.x;
  if (i < BN && pcount[i] > 0) {
    int pos = atomicAdd(cnt, 1);
    rowlist[pos] = i;
  }
}

__global__ void __launch_bounds__(256) normalize_kernel(
    const float* __restrict__ X, float* __restrict__ E, __bf16* __restrict__ Ebf) {
  const int tid  = threadIdx.x;
  const int lane = tid & 63;
  const int w    = tid >> 6;
  const int row  = blockIdx.x * 4 + w;
  float4 x = ((const float4*)(X + (size_t)row * DK))[lane];
  float ss = x.x * x.x + x.y * x.y + x.z * x.z + x.w * x.w;
  #pragma unroll
  for (int o = 32; o; o >>= 1) ss += __shfl_xor(ss, o);
  float nrm = fmaxf(sqrtf(ss), 1e-8f);
  float4 e;
  e.x = x.x / nrm; e.y = x.y / nrm; e.z = x.z / nrm; e.w = x.w / nrm;
  ((float4*)(E + (size_t)row * DK))[lane] = e;
  bf16_4 b;
  b[0] = (__bf16)e.x; b[1] = (__bf16)e.y; b[2] = (__bf16)e.z; b[3] = (__bf16)e.w;
  *(bf16_4*)(Ebf + (size_t)row * DK + lane * 4) = b;
}

__global__ void __launch_bounds__(256) pos_kernel(
    const float* __restrict__ E, const int2* __restrict__ pairs, float* __restrict__ pos) {
  const int tid  = threadIdx.x;
  const int lane = tid & 63;
  const int w    = tid >> 6;
  const int p    = blockIdx.x * 4 + w;
  int2 pr = pairs[p];
  float4 a = ((const float4*)(E + (size_t)pr.x * DK))[lane];
  float4 b = ((const float4*)(E + (size_t)pr.y * DK))[lane];
  float d = a.x * b.x + a.y * b.y + a.z * b.z + a.w * b.w;
  #pragma unroll
  for (int o = 32; o; o >>= 1) d += __shfl_xor(d, o);
  if (lane == 0) pos[p] = __expf(5.0f * d);
}

__global__ void __launch_bounds__(256) gemm_code_kernel(
    const __bf16* __restrict__ E, const int* __restrict__ rowlist,
    const int* __restrict__ countp, uint32_t* __restrict__ out4) {
  if ((int)blockIdx.y * 128 >= *countp) return;
  __shared__ __align__(16) __bf16 sA[128 * 32];
  __shared__ __align__(16) __bf16 sB[128 * 32];
  const int tid  = threadIdx.x;
  const int lane = tid & 63;
  const int w    = tid >> 6;
  const int wm   = w >> 1, wn = w & 1;
  const int trow = blockIdx.y * 128;
  const int tcol = blockIdx.x * 128;
  const int r0   = tid >> 2;
  const int seg  = tid & 3;

  const int ga0 = rowlist[trow + r0];
  const int ga1 = rowlist[trow + 64 + r0];
  const __bf16* pa0 = E + (size_t)ga0 * DK + seg * 8;
  const __bf16* pa1 = E + (size_t)ga1 * DK + seg * 8;
  const __bf16* pb0 = E + (size_t)(tcol + r0) * DK + seg * 8;
  const __bf16* pb1 = E + (size_t)(tcol + 64 + r0) * DK + seg * 8;
  __bf16* la0 = &sA[tid * 8];
  __bf16* la1 = &sA[2048 + tid * 8];
  __bf16* lb0 = &sB[tid * 8];
  __bf16* lb1 = &sB[2048 + tid * 8];

  f32x4 acc[4][4];
  #pragma unroll
  for (int i = 0; i < 4; ++i)
    #pragma unroll
    for (int j = 0; j < 4; ++j) {
      f32x4 z = {0.f, 0.f, 0.f, 0.f};
      acc[i][j] = z;
    }

  for (int kt = 0; kt < 8; ++kt) {
    const int k0 = kt * 32;
    __syncthreads();
    gload_lds16(pa0 + k0, la0);
    gload_lds16(pa1 + k0, la1);
    gload_lds16(pb0 + k0, lb0);
    gload_lds16(pb1 + k0, lb1);
    __syncthreads();
    bf16_8 af[4], bfg[4];
    #pragma unroll
    for (int q = 0; q < 4; ++q) {
      af[q]  = *(const bf16_8*)&sA[(wm * 64 + q * 16 + (lane & 15)) * 32 + (lane >> 4) * 8];
      bfg[q] = *(const bf16_8*)&sB[(wn * 64 + q * 16 + (lane & 15)) * 32 + (lane >> 4) * 8];
    }
    #pragma unroll
    for (int i = 0; i < 4; ++i)
      #pragma unroll
      for (int j = 0; j < 4; ++j)
        acc[i][j] = __builtin_amdgcn_mfma_f32_16x16x32_bf16(af[i], bfg[j], acc[i][j], 0, 0, 0);
  }

  const int crow = trow + wm * 64 + (lane >> 4) * 4;
  const int ccol = tcol + wn * 64 + (lane & 15);
  #pragma unroll
  for (int i = 0; i < 4; ++i) {
    const int gidx = (crow + i * 16) >> 2;
    #pragma unroll
    for (int j = 0; j < 4; ++j) {
      const int col = ccol + j * 16;
      uint32_t u = 0;
      #pragma unroll
      for (int r = 0; r < 4; ++r) {
        int c = (int)rintf(fmaf(acc[i][j][r], 250.0f, 128.0f));
        c = c < 1 ? 1 : (c > 255 ? 255 : c);
        u |= (uint32_t)c << (8 * r);
      }
      out4[(size_t)gidx * BN + col] = u;
    }
  }
}

__global__ void __launch_bounds__(256) row_stats4_kernel(
    const uint32_t* __restrict__ expc4, const int* __restrict__ rowlist,
    const int* __restrict__ countp, const int* __restrict__ pcount,
    const int* __restrict__ partners, float* __restrict__ S) {
  __shared__ unsigned hist[4][4][256];
  __shared__ unsigned total[4][256];
  __shared__ int plist[4][MAXP + 1];
  __shared__ int npl[4];
  __shared__ int growl[4];
  __shared__ int sh[2];
  __shared__ unsigned wtot[4];
  __shared__ float redf[4];
  const int g = blockIdx.x;
  const int cnt = *countp;
  if (g * 4 >= cnt) return;
  const int tid = threadIdx.x, lane = tid & 63, w = tid >> 6;

  uint4 rv[8];
  const uint4* src = (const uint4*)(expc4 + (size_t)g * BN);
  #pragma unroll
  for (int q = 0; q < 8; ++q) rv[q] = src[q * 256 + tid];

  if (tid < 4) {
    int rr = g * 4 + tid;
    int grow = (rr < cnt) ? rowlist[rr] : -1;
    growl[tid] = grow;
    int np = 0;
    if (grow >= 0) {
      np = pcount[grow]; if (np > MAXP) np = MAXP;
      for (int e = 0; e < np; ++e) plist[tid][e] = partners[grow * MAXP + e];
      plist[tid][np] = grow;
      np++;
    }
    npl[tid] = np;
  }
  #pragma unroll
  for (int k = 0; k < 16; ++k) ((unsigned*)hist)[k * 256 + tid] = 0;
  __syncthreads();

  #pragma unroll
  for (int r4 = 0; r4 < 4; ++r4) {
    const int np = npl[r4];
    for (int e = 0; e < np; ++e) {
      int c = plist[r4][e];
      int t = c >> 2;
      if ((t & 255) == tid) {
        unsigned* wp = (unsigned*)&rv[t >> 8];
        wp[c & 3] &= ~(0xFFu << (r4 * 8));
      }
    }
  }

  unsigned* h = (unsigned*)hist[w];
  #pragma unroll
  for (int q = 0; q < 8; ++q) {
    #pragma unroll
    for (int word = 0; word < 4; ++word) {
      unsigned dw = ((const unsigned*)&rv[q])[word];
      atomicAdd(&h[0 * 256 + (dw & 255u)], 1u);
      atomicAdd(&h[1 * 256 + ((dw >> 8) & 255u)], 1u);
      atomicAdd(&h[2 * 256 + ((dw >> 16) & 255u)], 1u);
      atomicAdd(&h[3 * 256 + (dw >> 24)], 1u);
    }
  }
  __syncthreads();
  #pragma unroll
  for (int r4 = 0; r4 < 4; ++r4)
    total[r4][tid] = hist[0][r4][tid] + hist[1][r4][tid] + hist[2][r4][tid] + hist[3][r4][tid];
  __syncthreads();

  const float val = __expf((float)(tid - 128) * QSTEP);
  for (int r4 = 0; r4 < 4; ++r4) {
    find_bin_256(total[r4], RANK_ASC, sh, wtot);
    const int b    = sh[0];
    const int need = (int)total[r4][b] - sh[1];
    float contrib = (tid > b) ? (float)total[r4][tid] * val
                  : (tid == b) ? (float)need * val : 0.f;
    #pragma unroll
    for (int o = 32; o; o >>= 1) contrib += __shfl_xor(contrib, o);
    __syncthreads();
    if (lane == 0) redf[w] = contrib;
    __syncthreads();
    if (tid == 0 && growl[r4] >= 0)
      S[growl[r4]] = redf[0] + redf[1] + redf[2] + redf[3];
    __syncthreads();
  }
}

__global__ void __launch_bounds__(256) finale_kernel(
    const float* __restrict__ pos, const int2* __restrict__ pairs,
    const float* __restrict__ S, float* __restrict__ out) {
  __shared__ uint32_t v[PN];
  __shared__ unsigned hist[256];
  __shared__ int sh[2];
  __shared__ unsigned wtot[4];
  __shared__ float red4[4];
  const int tid = threadIdx.x;
  for (int i = tid; i < PN; i += 256) v[i] = ((const uint32_t*)pos)[i];
  __syncthreads();
  int rank = 819;
  uint32_t prefix = 0;
  for (int pass = 0; pass < 4; ++pass) {
    const int shift = 24 - pass * 8;
    hist[tid] = 0;
    __syncthreads();
    for (int i = tid; i < PN; i += 256) {
      uint32_t x = v[i];
      bool match = (pass == 0) || ((x >> (shift + 8)) == (prefix >> (shift + 8)));
      if (match) atomicAdd(&hist[(x >> shift) & 255u], 1u);
    }
    __syncthreads();
    find_bin_256(hist, rank, sh, wtot);
    prefix |= ((uint32_t)sh[0]) << shift;
    rank = sh[1];
    __syncthreads();
  }
  float thr; __builtin_memcpy(&thr, &prefix, 4);

  float n = 0.f, sl = 0.f, sp = 0.f, sp2 = 0.f;
  for (int r = tid; r < PN; r += 256) {
    float p; uint32_t b = v[r]; __builtin_memcpy(&p, &b, 4);
    if (p <= thr) { n += 1.f; sl += __logf(p); sp += p; sp2 += p * p; }
  }
  float t = 0.f, u = 0.f, vv = 0.f;
  for (int c = tid; c < PN; c += 256) {
    int2 pr = pairs[c];
    float s1 = S[pr.x], s2 = S[pr.y];
    float i1 = 1.f / s1, i2 = 1.f / s2;
    t += __logf(s1) + __logf(s2);
    u += i1 + i2;
    vv += i1 * i1 + i2 * i2;
  }
  const float N   = block_sum4(n, red4);
  const float SL  = block_sum4(sl, red4);
  const float SP  = block_sum4(sp, red4);
  const float SP2 = block_sum4(sp2, red4);
  const float T   = block_sum4(t, red4);
  const float U   = block_sum4(u, red4);
  const float V   = block_sum4(vv, red4);
  if (tid == 0) {
    double num = (double)N * T - 2.0 * (double)PN * (double)SL
               + (double)SP * U - 0.5 * (double)SP2 * V;
    out[0] = (float)(num / (2.0 * (double)PN));
  }
}

// ---------------------------------------------------------------- launch
extern "C" void kernel_launch(void* const* d_in, const int* in_sizes, int n_in,
                              void* d_out, int out_size, void* d_ws, size_t ws_size,
                              hipStream_t stream) {
  char* w = (char*)d_ws;
  size_t off = 0;
  float*    E     = (float*)(w + off);    off += (size_t)BN * DK * 4;       // 8 MB
  __bf16*   Ebf   = (__bf16*)(w + off);   off += (size_t)BN * DK * 2;       // 4 MB
  float*    S     = (float*)(w + off);    off += (size_t)BN * 4;
  float*    pos   = (float*)(w + off);    off += (size_t)PN * 4;
  int*      pcnt  = (int*)(w + off);      off += (size_t)BN * 4;
  int*      parts = (int*)(w + off);      off += (size_t)BN * MAXP * 4;     // 512 KB
  int*      rlist = (int*)(w + off);      off += (size_t)BN * 4;
  int*      cnt   = (int*)(w + off);      off += 256;
  uint32_t* out4  = (uint32_t*)(w + off); off += (size_t)(BN / 4) * BN * 4; // 67 MB worst case

  Params prm;
  prm.emb   = (const float*)d_in[0];
  prm.pairs = (const int2*)d_in[1];
  prm.E = E; prm.Ebf = Ebf; prm.S = S; prm.pos = pos;
  prm.pcnt = pcnt; prm.parts = parts; prm.rlist = rlist; prm.cnt = cnt;
  prm.out4 = out4; prm.out = (float*)d_out;

  // Determine a co-residency-safe cooperative grid (host query, capture-safe).
  int maxB = 0;
  hipError_t qerr = hipOccupancyMaxActiveBlocksPerMultiprocessor(&maxB, mega_kernel, 256, 0);
  int grid = (qerr == hipSuccess && maxB > 0) ? maxB * NCU : NCU;
  if (grid > MAXGRID) grid = MAXGRID;

  void* kargs[] = { &prm };
  hipError_t lerr = hipLaunchCooperativeKernel((const void*)mega_kernel,
                                               dim3(grid), dim3(256), kargs, 0, stream);
  if (lerr != hipSuccess) {
    (void)hipGetLastError();   // clear; run the verified multi-kernel pipeline
    prep_clear_kernel<<<BN / 256, 256, 0, stream>>>(pcnt, rlist, cnt);
    normalize_kernel<<<BN / 4, 256, 0, stream>>>((const float*)d_in[0], E, Ebf);
    prep_pairs_kernel<<<PN / 256, 256, 0, stream>>>((const int2*)d_in[1], pcnt, parts);
    prep_compact_kernel<<<BN / 256, 256, 0, stream>>>(pcnt, rlist, cnt);
    pos_kernel<<<PN / 4, 256, 0, stream>>>(E, (const int2*)d_in[1], pos);
    gemm_code_kernel<<<dim3(BN / 128, BN / 128), 256, 0, stream>>>(Ebf, rlist, cnt, out4);
    row_stats4_kernel<<<BN / 4, 256, 0, stream>>>(out4, rlist, cnt, pcnt, parts, S);
    finale_kernel<<<1, 256, 0, stream>>>(pos, (const int2*)d_in[1], S, (float*)d_out);
  }
}

// Round 9
// 183.760 us; speedup vs baseline: 1.9741x; 1.9741x over previous
//
#include <hip/hip_runtime.h>
#include <stdint.h>

// Problem constants (fixed by the reference)
#define BN    8192    // batch
#define DK    256     // dim
#define PN    4096    // pairs
#define MAXP  16      // max partners tracked per row (Poisson(1); P(>16) ~ 1e-15)
#define RANK_ASC 6553 // ascending rank of first kept element (top-1639 = 0.8 quantile)
#define QSTEP 0.02f   // logit quantization step: code = round(5*cos/QSTEP)+128 in [1,255]

typedef __bf16  bf16_8 __attribute__((ext_vector_type(8)));
typedef __bf16  bf16_4 __attribute__((ext_vector_type(4)));
typedef float   f32x4  __attribute__((ext_vector_type(4)));

__device__ __forceinline__ void gload_lds16(const void* g, void* l) {
  __builtin_amdgcn_global_load_lds(
      (const __attribute__((address_space(1))) unsigned int*)g,
      (__attribute__((address_space(3))) unsigned int*)l, 16, 0, 0);
}

// ------------------------------------------------ parallel bin finder (256 bins)
__device__ __forceinline__ void find_bin_256(const unsigned* hist, int rank,
                                             int* sh, unsigned* wtot) {
  const int tid = threadIdx.x, lane = tid & 63, w = tid >> 6;
  unsigned x = hist[tid];
  unsigned pref = x;
  #pragma unroll
  for (int o = 1; o < 64; o <<= 1) {
    unsigned y = __shfl_up(pref, o);
    if (lane >= o) pref += y;
  }
  if (lane == 63) wtot[w] = pref;
  __syncthreads();
  unsigned woff = 0;
  for (int i = 0; i < w; ++i) woff += wtot[i];
  unsigned incl = pref + woff, excl = incl - x;
  if ((unsigned)rank >= excl && (unsigned)rank < incl) { sh[0] = tid; sh[1] = rank - (int)excl; }
  __syncthreads();
}

__device__ __forceinline__ float block_sum4(float x, float* red4) {
  const int lane = threadIdx.x & 63, w = threadIdx.x >> 6;
  #pragma unroll
  for (int o = 32; o; o >>= 1) x += __shfl_xor(x, o);
  __syncthreads();
  if (lane == 0) red4[w] = x;
  __syncthreads();
  return red4[0] + red4[1] + red4[2] + red4[3];
}

// ---------------- K1: clear ----------------
__global__ void __launch_bounds__(256) clear_kernel(int* pcount, int* rowlist, int* cnt) {
  const int i = blockIdx.x * 256 + threadIdx.x;
  pcount[i] = 0; rowlist[i] = 0;
  if (i == 0) cnt[0] = 0;
}

// ---------------- K2: normalize + pair scatter (independent; both need K1) ----------------
__global__ void __launch_bounds__(256) norm_pairs_kernel(
    const float* __restrict__ X, float* __restrict__ E, __bf16* __restrict__ Ebf,
    const int2* __restrict__ pairs, int* pcount, int* partners) {
  const int tid  = threadIdx.x;
  const int lane = tid & 63;
  const int wib  = tid >> 6;
  const int wv   = blockIdx.x * 4 + wib;
  const int nwave = gridDim.x * 4;

  for (int row = wv; row < BN; row += nwave) {
    float4 x = ((const float4*)(X + (size_t)row * DK))[lane];
    float ss = x.x * x.x + x.y * x.y + x.z * x.z + x.w * x.w;
    #pragma unroll
    for (int o = 32; o; o >>= 1) ss += __shfl_xor(ss, o);
    float nrm = fmaxf(sqrtf(ss), 1e-8f);
    float4 e;
    e.x = x.x / nrm; e.y = x.y / nrm; e.z = x.z / nrm; e.w = x.w / nrm;
    ((float4*)(E + (size_t)row * DK))[lane] = e;
    bf16_4 b;
    b[0] = (__bf16)e.x; b[1] = (__bf16)e.y; b[2] = (__bf16)e.z; b[3] = (__bf16)e.w;
    *(bf16_4*)(Ebf + (size_t)row * DK + lane * 4) = b;
  }

  const int p = blockIdx.x * 256 + tid;
  if (p < PN) {
    int2 pr = pairs[p];
    int ix = atomicAdd(&pcount[pr.x], 1);
    if (ix < MAXP) partners[pr.x * MAXP + ix] = pr.y;
    int iy = atomicAdd(&pcount[pr.y], 1);
    if (iy < MAXP) partners[pr.y * MAXP + iy] = pr.x;
  }
}

// ---------------- K3: compact + pos (independent; both need K2) ----------------
__global__ void __launch_bounds__(256) compact_pos_kernel(
    const int* __restrict__ pcount, int* rowlist, int* cnt,
    const float* __restrict__ E, const int2* __restrict__ pairs,
    float* __restrict__ pos) {
  const int tid  = threadIdx.x;
  const int lane = tid & 63;
  const int wib  = tid >> 6;
  const int gix  = blockIdx.x * 256 + tid;

  if (gix < BN && pcount[gix] > 0) {
    int ppos = atomicAdd(cnt, 1);
    rowlist[ppos] = gix;
  }

  const int wv = blockIdx.x * 4 + wib;
  const int nwave = gridDim.x * 4;
  for (int p = wv; p < PN; p += nwave) {
    int2 pr = pairs[p];
    float4 a = ((const float4*)(E + (size_t)pr.x * DK))[lane];
    float4 b = ((const float4*)(E + (size_t)pr.y * DK))[lane];
    float d = a.x * b.x + a.y * b.y + a.z * b.z + a.w * b.w;
    #pragma unroll
    for (int o = 32; o; o >>= 1) d += __shfl_xor(d, o);
    if (lane == 0) pos[p] = __expf(5.0f * d);
  }
}

// ---------------- K4: GEMM -> logit codes ----------------
// code = clamp(trunc(5*cos*50 + 128.5), 1, 255); 0 reserved for masked.
// Interleaved out: dword [rowgroup][col] = rows 4g..4g+3 (byte=row%4).
// 128x128 tile, BK=32, mfma 16x16x32 bf16, global_load_lds(16B) staging.
// 76 VGPR + 64 AGPR = 140 <= 170 -> 3 blocks/CU with (256,3).
__global__ void __launch_bounds__(256, 3) gemm_code_kernel(
    const __bf16* __restrict__ E, const int* __restrict__ rowlist,
    const int* __restrict__ countp, uint32_t* __restrict__ out4) {
  if ((int)blockIdx.y * 128 >= *countp) return;
  __shared__ __align__(16) __bf16 sA[128 * 32];
  __shared__ __align__(16) __bf16 sB[128 * 32];
  const int tid  = threadIdx.x;
  const int lane = tid & 63;
  const int w    = tid >> 6;
  const int wm   = w >> 1, wn = w & 1;
  const int trow = blockIdx.y * 128;
  const int tcol = blockIdx.x * 128;
  const int r0   = tid >> 2;
  const int seg  = tid & 3;

  const int ga0 = rowlist[trow + r0];
  const int ga1 = rowlist[trow + 64 + r0];
  const __bf16* pa0 = E + (size_t)ga0 * DK + seg * 8;
  const __bf16* pa1 = E + (size_t)ga1 * DK + seg * 8;
  const __bf16* pb0 = E + (size_t)(tcol + r0) * DK + seg * 8;
  const __bf16* pb1 = E + (size_t)(tcol + 64 + r0) * DK + seg * 8;
  __bf16* la0 = &sA[tid * 8];
  __bf16* la1 = &sA[2048 + tid * 8];
  __bf16* lb0 = &sB[tid * 8];
  __bf16* lb1 = &sB[2048 + tid * 8];

  f32x4 acc[4][4];
  #pragma unroll
  for (int i = 0; i < 4; ++i)
    #pragma unroll
    for (int j = 0; j < 4; ++j) {
      f32x4 z = {0.f, 0.f, 0.f, 0.f};
      acc[i][j] = z;
    }

  for (int kt = 0; kt < 8; ++kt) {
    const int k0 = kt * 32;
    __syncthreads();
    gload_lds16(pa0 + k0, la0);
    gload_lds16(pa1 + k0, la1);
    gload_lds16(pb0 + k0, lb0);
    gload_lds16(pb1 + k0, lb1);
    __syncthreads();
    bf16_8 af[4], bfg[4];
    #pragma unroll
    for (int q = 0; q < 4; ++q) {
      af[q]  = *(const bf16_8*)&sA[(wm * 64 + q * 16 + (lane & 15)) * 32 + (lane >> 4) * 8];
      bfg[q] = *(const bf16_8*)&sB[(wn * 64 + q * 16 + (lane & 15)) * 32 + (lane >> 4) * 8];
    }
    #pragma unroll
    for (int i = 0; i < 4; ++i)
      #pragma unroll
      for (int j = 0; j < 4; ++j)
        acc[i][j] = __builtin_amdgcn_mfma_f32_16x16x32_bf16(af[i], bfg[j], acc[i][j], 0, 0, 0);
  }

  const int crow = trow + wm * 64 + (lane >> 4) * 4;  // %4 == 0
  const int ccol = tcol + wn * 64 + (lane & 15);
  #pragma unroll
  for (int i = 0; i < 4; ++i) {
    const int gidx = (crow + i * 16) >> 2;
    #pragma unroll
    for (int j = 0; j < 4; ++j) {
      const int col = ccol + j * 16;
      uint32_t u = 0;
      #pragma unroll
      for (int r = 0; r < 4; ++r) {
        // trunc(x+0.5) == round for the positive in-range codes; negatives clamp to 1
        int c = (int)fmaf(acc[i][j][r], 250.0f, 128.5f);
        c = c < 1 ? 1 : (c > 255 ? 255 : c);
        u |= (uint32_t)c << (8 * r);
      }
      out4[(size_t)gidx * BN + col] = u;
    }
  }
}

// ---------------- K5: row stats from code histogram ----------------
// One block per group of 4 compacted rows. Code byte == radix bin (uniform in
// logit space -> ~100 occupied bins). One histogram pass, exact select on
// quantized values: S = sum_{bin>b} cnt*val(bin) + need*val(b).
__global__ void __launch_bounds__(256) row_stats4_kernel(
    const uint32_t* __restrict__ expc4, const int* __restrict__ rowlist,
    const int* __restrict__ countp, const int* __restrict__ pcount,
    const int* __restrict__ partners, float* __restrict__ S) {
  __shared__ unsigned hist[4][4][256];   // [wave][r4][bin] = 16 KB
  __shared__ unsigned total[4][256];     // 4 KB
  __shared__ int plist[4][MAXP + 1];
  __shared__ int npl[4];
  __shared__ int growl[4];
  __shared__ int sh[2];
  __shared__ unsigned wtot[4];
  __shared__ float redf[4];
  const int g = blockIdx.x;
  const int cnt = *countp;
  if (g * 4 >= cnt) return;
  const int tid = threadIdx.x, lane = tid & 63, w = tid >> 6;

  uint4 rv[8];
  const uint4* src = (const uint4*)(expc4 + (size_t)g * BN);
  #pragma unroll
  for (int q = 0; q < 8; ++q) rv[q] = src[q * 256 + tid];

  if (tid < 4) {
    int rr = g * 4 + tid;
    int grow = (rr < cnt) ? rowlist[rr] : -1;
    growl[tid] = grow;
    int np = 0;
    if (grow >= 0) {
      np = pcount[grow]; if (np > MAXP) np = MAXP;
      for (int e = 0; e < np; ++e) plist[tid][e] = partners[grow * MAXP + e];
      plist[tid][np] = grow;   // diagonal
      np++;
    }
    npl[tid] = np;
  }
  #pragma unroll
  for (int k = 0; k < 16; ++k) ((unsigned*)hist)[k * 256 + tid] = 0;
  __syncthreads();

  // mask partner/diagonal columns (zero byte -> bin 0, never selected)
  #pragma unroll
  for (int r4 = 0; r4 < 4; ++r4) {
    const int np = npl[r4];
    for (int e = 0; e < np; ++e) {
      int c = plist[r4][e];
      int t = c >> 2;
      if ((t & 255) == tid) {
        unsigned* wp = (unsigned*)&rv[t >> 8];
        wp[c & 3] &= ~(0xFFu << (r4 * 8));
      }
    }
  }

  unsigned* h = (unsigned*)hist[w];
  #pragma unroll
  for (int q = 0; q < 8; ++q) {
    #pragma unroll
    for (int word = 0; word < 4; ++word) {
      unsigned dw = ((const unsigned*)&rv[q])[word];
      atomicAdd(&h[0 * 256 + (dw & 255u)], 1u);
      atomicAdd(&h[1 * 256 + ((dw >> 8) & 255u)], 1u);
      atomicAdd(&h[2 * 256 + ((dw >> 16) & 255u)], 1u);
      atomicAdd(&h[3 * 256 + (dw >> 24)], 1u);
    }
  }
  __syncthreads();
  #pragma unroll
  for (int r4 = 0; r4 < 4; ++r4)
    total[r4][tid] = hist[0][r4][tid] + hist[1][r4][tid] + hist[2][r4][tid] + hist[3][r4][tid];
  __syncthreads();

  const float val = __expf((float)(tid - 128) * QSTEP);
  for (int r4 = 0; r4 < 4; ++r4) {
    find_bin_256(total[r4], RANK_ASC, sh, wtot);
    const int b    = sh[0];
    const int need = (int)total[r4][b] - sh[1];
    float contrib = (tid > b) ? (float)total[r4][tid] * val
                  : (tid == b) ? (float)need * val : 0.f;
    #pragma unroll
    for (int o = 32; o; o >>= 1) contrib += __shfl_xor(contrib, o);
    __syncthreads();
    if (lane == 0) redf[w] = contrib;
    __syncthreads();
    if (tid == 0 && growl[r4] >= 0)
      S[growl[r4]] = redf[0] + redf[1] + redf[2] + redf[3];
    __syncthreads();
  }
}

// ---------------- K6: finale ----------------
// Exact radix select of pos rank 819 -> thr; factorized loss:
// log1p(S/p) = logS - logp + p/S - p^2/(2S^2) + O((p/S)^3), p/S <~ 3e-4
// loss = (n*T - 2P*sl + sp*U - 0.5*sp2*V) / (2P)
__global__ void __launch_bounds__(256) finale_kernel(
    const float* __restrict__ pos, const int2* __restrict__ pairs,
    const float* __restrict__ S, float* __restrict__ out) {
  __shared__ uint32_t v[PN];
  __shared__ unsigned hist[256];
  __shared__ int sh[2];
  __shared__ unsigned wtot[4];
  __shared__ float red4[4];
  const int tid = threadIdx.x;
  for (int i = tid; i < PN; i += 256) v[i] = ((const uint32_t*)pos)[i];
  __syncthreads();
  int rank = 819;                 // 0.2 * 4095 exactly
  uint32_t prefix = 0;
  for (int pass = 0; pass < 4; ++pass) {
    const int shift = 24 - pass * 8;
    hist[tid] = 0;
    __syncthreads();
    for (int i = tid; i < PN; i += 256) {
      uint32_t x = v[i];
      bool match = (pass == 0) || ((x >> (shift + 8)) == (prefix >> (shift + 8)));
      if (match) atomicAdd(&hist[(x >> shift) & 255u], 1u);
    }
    __syncthreads();
    find_bin_256(hist, rank, sh, wtot);
    prefix |= ((uint32_t)sh[0]) << shift;
    rank = sh[1];
    __syncthreads();
  }
  float thr; __builtin_memcpy(&thr, &prefix, 4);

  float n = 0.f, sl = 0.f, sp = 0.f, sp2 = 0.f;
  for (int r = tid; r < PN; r += 256) {
    float p; uint32_t b = v[r]; __builtin_memcpy(&p, &b, 4);
    if (p <= thr) { n += 1.f; sl += __logf(p); sp += p; sp2 += p * p; }
  }
  float t = 0.f, u = 0.f, vv = 0.f;
  for (int c = tid; c < PN; c += 256) {
    int2 pr = pairs[c];
    float s1 = S[pr.x], s2 = S[pr.y];
    float i1 = 1.f / s1, i2 = 1.f / s2;
    t += __logf(s1) + __logf(s2);
    u += i1 + i2;
    vv += i1 * i1 + i2 * i2;
  }
  const float N   = block_sum4(n, red4);
  const float SL  = block_sum4(sl, red4);
  const float SP  = block_sum4(sp, red4);
  const float SP2 = block_sum4(sp2, red4);
  const float T   = block_sum4(t, red4);
  const float U   = block_sum4(u, red4);
  const float V   = block_sum4(vv, red4);
  if (tid == 0) {
    double num = (double)N * T - 2.0 * (double)PN * (double)SL
               + (double)SP * U - 0.5 * (double)SP2 * V;
    out[0] = (float)(num / (2.0 * (double)PN));
  }
}

// ---------------------------------------------------------------- launch
extern "C" void kernel_launch(void* const* d_in, const int* in_sizes, int n_in,
                              void* d_out, int out_size, void* d_ws, size_t ws_size,
                              hipStream_t stream) {
  const float* emb  = (const float*)d_in[0];
  const int2* pairs = (const int2*)d_in[1];
  float* out = (float*)d_out;

  char* w = (char*)d_ws;
  size_t off = 0;
  float*    E     = (float*)(w + off);    off += (size_t)BN * DK * 4;       // 8 MB
  __bf16*   Ebf   = (__bf16*)(w + off);   off += (size_t)BN * DK * 2;       // 4 MB
  float*    S     = (float*)(w + off);    off += (size_t)BN * 4;
  float*    pos   = (float*)(w + off);    off += (size_t)PN * 4;
  int*      pcnt  = (int*)(w + off);      off += (size_t)BN * 4;
  int*      parts = (int*)(w + off);      off += (size_t)BN * MAXP * 4;     // 512 KB
  int*      rlist = (int*)(w + off);      off += (size_t)BN * 4;
  int*      cnt   = (int*)(w + off);      off += 256;
  uint32_t* out4  = (uint32_t*)(w + off); off += (size_t)(BN / 4) * BN * 4; // 67 MB worst case

  clear_kernel<<<BN / 256, 256, 0, stream>>>(pcnt, rlist, cnt);
  norm_pairs_kernel<<<512, 256, 0, stream>>>(emb, E, Ebf, pairs, pcnt, parts);
  compact_pos_kernel<<<BN / 256, 256, 0, stream>>>(pcnt, rlist, cnt, E, pairs, pos);
  gemm_code_kernel<<<dim3(BN / 128, BN / 128), 256, 0, stream>>>(Ebf, rlist, cnt, out4);
  row_stats4_kernel<<<BN / 4, 256, 0, stream>>>(out4, rlist, cnt, pcnt, parts, S);
  finale_kernel<<<1, 256, 0, stream>>>(pos, pairs, S, out);
}

// Round 10
// 161.090 us; speedup vs baseline: 2.2519x; 1.1407x over previous
//
#include <hip/hip_runtime.h>
#include <stdint.h>

// Problem constants (fixed by the reference)
#define BN    8192    // batch
#define DK    256     // dim
#define PN    4096    // pairs
#define MAXP  16      // max partners tracked per row (Poisson(1); P(>16) ~ 1e-15)
#define RANK_ASC 6553 // ascending rank of first kept element (top-1639 = 0.8 quantile)
#define QSTEP 0.02f   // logit quantization step: code = round(5*cos/QSTEP)+128 in [1,255]

typedef __bf16  bf16_8 __attribute__((ext_vector_type(8)));
typedef __bf16  bf16_4 __attribute__((ext_vector_type(4)));
typedef float   f32x4  __attribute__((ext_vector_type(4)));

__device__ __forceinline__ void gload_lds16(const void* g, void* l) {
  __builtin_amdgcn_global_load_lds(
      (const __attribute__((address_space(1))) unsigned int*)g,
      (__attribute__((address_space(3))) unsigned int*)l, 16, 0, 0);
}

// ------------------------------------------------ parallel bin finder (256 bins)
__device__ __forceinline__ void find_bin_256(const unsigned* hist, int rank,
                                             int* sh, unsigned* wtot) {
  const int tid = threadIdx.x, lane = tid & 63, w = tid >> 6;
  unsigned x = hist[tid];
  unsigned pref = x;
  #pragma unroll
  for (int o = 1; o < 64; o <<= 1) {
    unsigned y = __shfl_up(pref, o);
    if (lane >= o) pref += y;
  }
  if (lane == 63) wtot[w] = pref;
  __syncthreads();
  unsigned woff = 0;
  for (int i = 0; i < w; ++i) woff += wtot[i];
  unsigned incl = pref + woff, excl = incl - x;
  if ((unsigned)rank >= excl && (unsigned)rank < incl) { sh[0] = tid; sh[1] = rank - (int)excl; }
  __syncthreads();
}

__device__ __forceinline__ float block_sum4(float x, float* red4) {
  const int lane = threadIdx.x & 63, w = threadIdx.x >> 6;
  #pragma unroll
  for (int o = 32; o; o >>= 1) x += __shfl_xor(x, o);
  __syncthreads();
  if (lane == 0) red4[w] = x;
  __syncthreads();
  return red4[0] + red4[1] + red4[2] + red4[3];
}

// ---------------- K1: clear ----------------
__global__ void __launch_bounds__(256) clear_kernel(int* pcount, int* rowlist, int* cnt) {
  const int i = blockIdx.x * 256 + threadIdx.x;
  pcount[i] = 0; rowlist[i] = 0;
  if (i == 0) cnt[0] = 0;
}

// ---------------- K2: normalize (1 row/wave) + pair scatter (blocks 0..15) ----------------
__global__ void __launch_bounds__(256) norm_pairs_kernel(
    const float* __restrict__ X, float* __restrict__ E, __bf16* __restrict__ Ebf,
    const int2* __restrict__ pairs, int* pcount, int* partners) {
  const int tid  = threadIdx.x;
  const int lane = tid & 63;
  const int wib  = tid >> 6;
  const int row  = blockIdx.x * 4 + wib;      // grid 2048 -> rows 0..8191

  float4 x = ((const float4*)(X + (size_t)row * DK))[lane];
  float ss = x.x * x.x + x.y * x.y + x.z * x.z + x.w * x.w;
  #pragma unroll
  for (int o = 32; o; o >>= 1) ss += __shfl_xor(ss, o);
  float nrm = fmaxf(sqrtf(ss), 1e-8f);
  float4 e;
  e.x = x.x / nrm; e.y = x.y / nrm; e.z = x.z / nrm; e.w = x.w / nrm;
  ((float4*)(E + (size_t)row * DK))[lane] = e;
  bf16_4 b;
  b[0] = (__bf16)e.x; b[1] = (__bf16)e.y; b[2] = (__bf16)e.z; b[3] = (__bf16)e.w;
  *(bf16_4*)(Ebf + (size_t)row * DK + lane * 4) = b;

  const int p = blockIdx.x * 256 + tid;
  if (p < PN) {
    int2 pr = pairs[p];
    int ix = atomicAdd(&pcount[pr.x], 1);
    if (ix < MAXP) partners[pr.x * MAXP + ix] = pr.y;
    int iy = atomicAdd(&pcount[pr.y], 1);
    if (iy < MAXP) partners[pr.y * MAXP + iy] = pr.x;
  }
}

// ---------------- K3: compact (blocks 0..31) + pos (1 pair/wave) ----------------
__global__ void __launch_bounds__(256) compact_pos_kernel(
    const int* __restrict__ pcount, int* rowlist, int* cnt,
    const float* __restrict__ E, const int2* __restrict__ pairs,
    float* __restrict__ pos) {
  const int tid  = threadIdx.x;
  const int lane = tid & 63;
  const int wib  = tid >> 6;
  const int gix  = blockIdx.x * 256 + tid;

  if (gix < BN && pcount[gix] > 0) {
    int ppos = atomicAdd(cnt, 1);
    rowlist[ppos] = gix;
  }

  const int p = blockIdx.x * 4 + wib;         // grid 1024 -> pairs 0..4095
  int2 pr = pairs[p];
  float4 a = ((const float4*)(E + (size_t)pr.x * DK))[lane];
  float4 b = ((const float4*)(E + (size_t)pr.y * DK))[lane];
  float d = a.x * b.x + a.y * b.y + a.z * b.z + a.w * b.w;
  #pragma unroll
  for (int o = 32; o; o >>= 1) d += __shfl_xor(d, o);
  if (lane == 0) pos[p] = __expf(5.0f * d);
}

// ---------------- K4: GEMM -> logit codes ----------------
// code = clamp(trunc(5*cos*50 + 128.5), 1, 255); 0 reserved for masked.
// Interleaved out: dword [rowgroup][col] = rows 4g..4g+3 (byte=row%4).
// 128x128 tile, BK=32, mfma 16x16x32 bf16, global_load_lds(16B) staging.
__global__ void __launch_bounds__(256) gemm_code_kernel(
    const __bf16* __restrict__ E, const int* __restrict__ rowlist,
    const int* __restrict__ countp, uint32_t* __restrict__ out4) {
  if ((int)blockIdx.y * 128 >= *countp) return;
  __shared__ __align__(16) __bf16 sA[128 * 32];
  __shared__ __align__(16) __bf16 sB[128 * 32];
  const int tid  = threadIdx.x;
  const int lane = tid & 63;
  const int w    = tid >> 6;
  const int wm   = w >> 1, wn = w & 1;
  const int trow = blockIdx.y * 128;
  const int tcol = blockIdx.x * 128;
  const int r0   = tid >> 2;
  const int seg  = tid & 3;

  const int ga0 = rowlist[trow + r0];
  const int ga1 = rowlist[trow + 64 + r0];
  const __bf16* pa0 = E + (size_t)ga0 * DK + seg * 8;
  const __bf16* pa1 = E + (size_t)ga1 * DK + seg * 8;
  const __bf16* pb0 = E + (size_t)(tcol + r0) * DK + seg * 8;
  const __bf16* pb1 = E + (size_t)(tcol + 64 + r0) * DK + seg * 8;
  __bf16* la0 = &sA[tid * 8];
  __bf16* la1 = &sA[2048 + tid * 8];
  __bf16* lb0 = &sB[tid * 8];
  __bf16* lb1 = &sB[2048 + tid * 8];

  f32x4 acc[4][4];
  #pragma unroll
  for (int i = 0; i < 4; ++i)
    #pragma unroll
    for (int j = 0; j < 4; ++j) {
      f32x4 z = {0.f, 0.f, 0.f, 0.f};
      acc[i][j] = z;
    }

  for (int kt = 0; kt < 8; ++kt) {
    const int k0 = kt * 32;
    __syncthreads();
    gload_lds16(pa0 + k0, la0);
    gload_lds16(pa1 + k0, la1);
    gload_lds16(pb0 + k0, lb0);
    gload_lds16(pb1 + k0, lb1);
    __syncthreads();
    bf16_8 af[4], bfg[4];
    #pragma unroll
    for (int q = 0; q < 4; ++q) {
      af[q]  = *(const bf16_8*)&sA[(wm * 64 + q * 16 + (lane & 15)) * 32 + (lane >> 4) * 8];
      bfg[q] = *(const bf16_8*)&sB[(wn * 64 + q * 16 + (lane & 15)) * 32 + (lane >> 4) * 8];
    }
    #pragma unroll
    for (int i = 0; i < 4; ++i)
      #pragma unroll
      for (int j = 0; j < 4; ++j)
        acc[i][j] = __builtin_amdgcn_mfma_f32_16x16x32_bf16(af[i], bfg[j], acc[i][j], 0, 0, 0);
  }

  const int crow = trow + wm * 64 + (lane >> 4) * 4;  // %4 == 0
  const int ccol = tcol + wn * 64 + (lane & 15);
  #pragma unroll
  for (int i = 0; i < 4; ++i) {
    const int gidx = (crow + i * 16) >> 2;
    #pragma unroll
    for (int j = 0; j < 4; ++j) {
      const int col = ccol + j * 16;
      uint32_t u = 0;
      #pragma unroll
      for (int r = 0; r < 4; ++r) {
        // trunc(x+0.5) == round for positive in-range codes; negatives clamp to 1
        int c = (int)fmaf(acc[i][j][r], 250.0f, 128.5f);
        c = c < 1 ? 1 : (c > 255 ? 255 : c);
        u |= (uint32_t)c << (8 * r);
      }
      out4[(size_t)gidx * BN + col] = u;
    }
  }
}

// ---------------- K5: row stats from code histogram ----------------
// One block per group of 4 compacted rows. Code byte == radix bin (uniform in
// logit space -> ~100 occupied bins). One histogram pass, exact select on
// quantized values: S = sum_{bin>b} cnt*val(bin) + need*val(b).
__global__ void __launch_bounds__(256) row_stats4_kernel(
    const uint32_t* __restrict__ expc4, const int* __restrict__ rowlist,
    const int* __restrict__ countp, const int* __restrict__ pcount,
    const int* __restrict__ partners, float* __restrict__ S) {
  __shared__ unsigned hist[4][4][256];   // [wave][r4][bin] = 16 KB
  __shared__ unsigned total[4][256];     // 4 KB
  __shared__ int plist[4][MAXP + 1];
  __shared__ int npl[4];
  __shared__ int growl[4];
  __shared__ int sh[2];
  __shared__ unsigned wtot[4];
  __shared__ float redf[4];
  const int g = blockIdx.x;
  const int cnt = *countp;
  if (g * 4 >= cnt) return;
  const int tid = threadIdx.x, lane = tid & 63, w = tid >> 6;

  uint4 rv[8];
  const uint4* src = (const uint4*)(expc4 + (size_t)g * BN);
  #pragma unroll
  for (int q = 0; q < 8; ++q) rv[q] = src[q * 256 + tid];

  if (tid < 4) {
    int rr = g * 4 + tid;
    int grow = (rr < cnt) ? rowlist[rr] : -1;
    growl[tid] = grow;
    int np = 0;
    if (grow >= 0) {
      np = pcount[grow]; if (np > MAXP) np = MAXP;
      for (int e = 0; e < np; ++e) plist[tid][e] = partners[grow * MAXP + e];
      plist[tid][np] = grow;   // diagonal
      np++;
    }
    npl[tid] = np;
  }
  #pragma unroll
  for (int k = 0; k < 16; ++k) ((unsigned*)hist)[k * 256 + tid] = 0;
  __syncthreads();

  // mask partner/diagonal columns (zero byte -> bin 0, never selected)
  #pragma unroll
  for (int r4 = 0; r4 < 4; ++r4) {
    const int np = npl[r4];
    for (int e = 0; e < np; ++e) {
      int c = plist[r4][e];
      int t = c >> 2;
      if ((t & 255) == tid) {
        unsigned* wp = (unsigned*)&rv[t >> 8];
        wp[c & 3] &= ~(0xFFu << (r4 * 8));
      }
    }
  }

  unsigned* h = (unsigned*)hist[w];
  #pragma unroll
  for (int q = 0; q < 8; ++q) {
    #pragma unroll
    for (int word = 0; word < 4; ++word) {
      unsigned dw = ((const unsigned*)&rv[q])[word];
      atomicAdd(&h[0 * 256 + (dw & 255u)], 1u);
      atomicAdd(&h[1 * 256 + ((dw >> 8) & 255u)], 1u);
      atomicAdd(&h[2 * 256 + ((dw >> 16) & 255u)], 1u);
      atomicAdd(&h[3 * 256 + (dw >> 24)], 1u);
    }
  }
  __syncthreads();
  #pragma unroll
  for (int r4 = 0; r4 < 4; ++r4)
    total[r4][tid] = hist[0][r4][tid] + hist[1][r4][tid] + hist[2][r4][tid] + hist[3][r4][tid];
  __syncthreads();

  const float val = __expf((float)(tid - 128) * QSTEP);
  for (int r4 = 0; r4 < 4; ++r4) {
    find_bin_256(total[r4], RANK_ASC, sh, wtot);
    const int b    = sh[0];
    const int need = (int)total[r4][b] - sh[1];
    float contrib = (tid > b) ? (float)total[r4][tid] * val
                  : (tid == b) ? (float)need * val : 0.f;
    #pragma unroll
    for (int o = 32; o; o >>= 1) contrib += __shfl_xor(contrib, o);
    __syncthreads();
    if (lane == 0) redf[w] = contrib;
    __syncthreads();
    if (tid == 0 && growl[r4] >= 0)
      S[growl[r4]] = redf[0] + redf[1] + redf[2] + redf[3];
    __syncthreads();
  }
}

// ---------------- K6: finale ----------------
// Exact radix select of pos rank 819 -> thr; factorized loss:
// log1p(S/p) = logS - logp + p/S - p^2/(2S^2) + O((p/S)^3), p/S <~ 3e-4
// loss = (n*T - 2P*sl + sp*U - 0.5*sp2*V) / (2P)
__global__ void __launch_bounds__(256) finale_kernel(
    const float* __restrict__ pos, const int2* __restrict__ pairs,
    const float* __restrict__ S, float* __restrict__ out) {
  __shared__ uint32_t v[PN];
  __shared__ unsigned hist[256];
  __shared__ int sh[2];
  __shared__ unsigned wtot[4];
  __shared__ float red4[4];
  const int tid = threadIdx.x;
  for (int i = tid; i < PN; i += 256) v[i] = ((const uint32_t*)pos)[i];
  __syncthreads();
  int rank = 819;                 // 0.2 * 4095 exactly
  uint32_t prefix = 0;
  for (int pass = 0; pass < 4; ++pass) {
    const int shift = 24 - pass * 8;
    hist[tid] = 0;
    __syncthreads();
    for (int i = tid; i < PN; i += 256) {
      uint32_t x = v[i];
      bool match = (pass == 0) || ((x >> (shift + 8)) == (prefix >> (shift + 8)));
      if (match) atomicAdd(&hist[(x >> shift) & 255u], 1u);
    }
    __syncthreads();
    find_bin_256(hist, rank, sh, wtot);
    prefix |= ((uint32_t)sh[0]) << shift;
    rank = sh[1];
    __syncthreads();
  }
  float thr; __builtin_memcpy(&thr, &prefix, 4);

  float n = 0.f, sl = 0.f, sp = 0.f, sp2 = 0.f;
  for (int r = tid; r < PN; r += 256) {
    float p; uint32_t b = v[r]; __builtin_memcpy(&p, &b, 4);
    if (p <= thr) { n += 1.f; sl += __logf(p); sp += p; sp2 += p * p; }
  }
  float t = 0.f, u = 0.f, vv = 0.f;
  for (int c = tid; c < PN; c += 256) {
    int2 pr = pairs[c];
    float s1 = S[pr.x], s2 = S[pr.y];
    float i1 = 1.f / s1, i2 = 1.f / s2;
    t += __logf(s1) + __logf(s2);
    u += i1 + i2;
    vv += i1 * i1 + i2 * i2;
  }
  const float N   = block_sum4(n, red4);
  const float SL  = block_sum4(sl, red4);
  const float SP  = block_sum4(sp, red4);
  const float SP2 = block_sum4(sp2, red4);
  const float T   = block_sum4(t, red4);
  const float U   = block_sum4(u, red4);
  const float V   = block_sum4(vv, red4);
  if (tid == 0) {
    double num = (double)N * T - 2.0 * (double)PN * (double)SL
               + (double)SP * U - 0.5 * (double)SP2 * V;
    out[0] = (float)(num / (2.0 * (double)PN));
  }
}

// ---------------------------------------------------------------- launch
extern "C" void kernel_launch(void* const* d_in, const int* in_sizes, int n_in,
                              void* d_out, int out_size, void* d_ws, size_t ws_size,
                              hipStream_t stream) {
  const float* emb  = (const float*)d_in[0];
  const int2* pairs = (const int2*)d_in[1];
  float* out = (float*)d_out;

  char* w = (char*)d_ws;
  size_t off = 0;
  float*    E     = (float*)(w + off);    off += (size_t)BN * DK * 4;       // 8 MB
  __bf16*   Ebf   = (__bf16*)(w + off);   off += (size_t)BN * DK * 2;       // 4 MB
  float*    S     = (float*)(w + off);    off += (size_t)BN * 4;
  float*    pos   = (float*)(w + off);    off += (size_t)PN * 4;
  int*      pcnt  = (int*)(w + off);      off += (size_t)BN * 4;
  int*      parts = (int*)(w + off);      off += (size_t)BN * MAXP * 4;     // 512 KB
  int*      rlist = (int*)(w + off);      off += (size_t)BN * 4;
  int*      cnt   = (int*)(w + off);      off += 256;
  uint32_t* out4  = (uint32_t*)(w + off); off += (size_t)(BN / 4) * BN * 4; // 67 MB worst case

  clear_kernel<<<BN / 256, 256, 0, stream>>>(pcnt, rlist, cnt);
  norm_pairs_kernel<<<BN / 4, 256, 0, stream>>>(emb, E, Ebf, pairs, pcnt, parts);
  compact_pos_kernel<<<PN / 4, 256, 0, stream>>>(pcnt, rlist, cnt, E, pairs, pos);
  gemm_code_kernel<<<dim3(BN / 128, BN / 128), 256, 0, stream>>>(Ebf, rlist, cnt, out4);
  row_stats4_kernel<<<BN / 4, 256, 0, stream>>>(out4, rlist, cnt, pcnt, parts, S);
  finale_kernel<<<1, 256, 0, stream>>>(pos, pairs, S, out);
}